// Round 4
// baseline (822.344 us; speedup 1.0000x reference)
//
#include <hip/hip_runtime.h>
#include <stdint.h>

// HunyuanVideo attn block: rmsnorm -> qkv proj -> frame-causal attention -> out proj + residual
// B=1, C=512, T=8, H=W=32 -> S=8192, frame block = 1024.
// v3: attention: K+V both staged via global_load_lds (K XOR-swizzled src, swizzled read),
//     double-buffered, q=32 per wave (halves LDS bytes/FLOP), 256 uniform blocks (1/CU, no tail).

typedef __bf16 bf16;
typedef __bf16 bf16x8 __attribute__((ext_vector_type(8)));
typedef float f32x4 __attribute__((ext_vector_type(4)));
typedef uint32_t u32;
typedef uint32_t u32x2 __attribute__((ext_vector_type(2)));

#define MFMA16(a, b, c) __builtin_amdgcn_mfma_f32_16x16x32_bf16((a), (b), (c), 0, 0, 0)

__device__ __forceinline__ u32 pack2(float a, float b) {
  union { bf16 h[2]; u32 u; } x;
  x.h[0] = (bf16)a;
  x.h[1] = (bf16)b;
  return x.u;
}

__device__ __forceinline__ void async_copy16(const bf16* gsrc, bf16* ldst) {
  __builtin_amdgcn_global_load_lds(
      (const __attribute__((address_space(1))) void*)gsrc,
      (__attribute__((address_space(3))) void*)ldst, 16, 0, 0);
}

// ---------------- weights fp32 -> bf16 ----------------
__global__ void cvt_w_kernel(const float* __restrict__ a, const float* __restrict__ b,
                             const float* __restrict__ c, const float* __restrict__ d,
                             bf16* __restrict__ out) {
  int i = blockIdx.x * 256 + threadIdx.x;
  const int N = 512 * 512;
  out[i]         = (bf16)a[i];
  out[N + i]     = (bf16)b[i];
  out[2 * N + i] = (bf16)c[i];
  out[3 * N + i] = (bf16)d[i];
}

// ---------------- rmsnorm over C + transpose to [S][C] bf16 ----------------
__global__ __launch_bounds__(256) void rmsnorm_kernel(const float* __restrict__ x,
                                                      const float* __restrict__ gamma,
                                                      bf16* __restrict__ xn) {
  const int S = 8192;
  __shared__ float sums[4][64];
  int ts = threadIdx.x & 63, tc = threadIdx.x >> 6;
  int s = blockIdx.x * 64 + ts;
  float acc = 0.f;
  for (int c = tc * 128; c < tc * 128 + 128; ++c) {
    float v = x[(size_t)c * S + s];
    acc += v * v;
  }
  sums[tc][ts] = acc;
  __syncthreads();
  float tot = sums[0][ts] + sums[1][ts] + sums[2][ts] + sums[3][ts];
  float kk = 22.62741699796952f / fmaxf(sqrtf(tot), 1e-12f);
  for (int c0 = tc * 128; c0 < tc * 128 + 128; c0 += 8) {
    bf16x8 o;
#pragma unroll
    for (int j = 0; j < 8; ++j) o[j] = (bf16)(x[(size_t)(c0 + j) * S + s] * kk * gamma[c0 + j]);
    *(bf16x8*)(xn + (size_t)s * 512 + c0) = o;
  }
}

// ---------------- NT GEMM: C[m,n] = sum_k A[m,k]*B[n,k], K=512 ----------------
template <int EPI>
__global__ __launch_bounds__(256) void gemm_nt_kernel(const bf16* __restrict__ A,
                                                      const bf16* __restrict__ B,
                                                      const float* __restrict__ bias,
                                                      const float* __restrict__ resid,
                                                      void* __restrict__ Cout, int M, int N,
                                                      int nbn) {
  __shared__ bf16 a_lds[128 * 72];
  __shared__ bf16 b_lds[128 * 72];
  const int K = 512;
  int bm = blockIdx.x / nbn, bn = blockIdx.x % nbn;
  int m0 = bm * 128, n0 = bn * 128;
  int tid = threadIdx.x, lane = tid & 63;
  int wid = tid >> 6;
  int wm = (wid >> 1) * 64, wn = (wid & 1) * 64;
  int l15 = lane & 15, l4 = lane >> 4;
  f32x4 acc[4][4];
#pragma unroll
  for (int i = 0; i < 4; ++i)
#pragma unroll
    for (int j = 0; j < 4; ++j) acc[i][j] = (f32x4){0.f, 0.f, 0.f, 0.f};

  for (int k0 = 0; k0 < K; k0 += 64) {
    __syncthreads();
#pragma unroll
    for (int i = 0; i < 4; ++i) {
      int lin = i * 2048 + tid * 8;
      int r = lin >> 6, c = lin & 63;
      *(bf16x8*)(a_lds + r * 72 + c) = *(const bf16x8*)(A + (size_t)(m0 + r) * K + k0 + c);
      *(bf16x8*)(b_lds + r * 72 + c) = *(const bf16x8*)(B + (size_t)(n0 + r) * K + k0 + c);
    }
    __syncthreads();
#pragma unroll
    for (int kk = 0; kk < 2; ++kk) {
      bf16x8 af[4], bfr[4];
#pragma unroll
      for (int i = 0; i < 4; ++i)
        af[i] = *(bf16x8*)(a_lds + (wm + i * 16 + l15) * 72 + kk * 32 + l4 * 8);
#pragma unroll
      for (int j = 0; j < 4; ++j)
        bfr[j] = *(bf16x8*)(b_lds + (wn + j * 16 + l15) * 72 + kk * 32 + l4 * 8);
#pragma unroll
      for (int i = 0; i < 4; ++i)
#pragma unroll
        for (int j = 0; j < 4; ++j) acc[i][j] = MFMA16(af[i], bfr[j], acc[i][j]);
    }
  }
#pragma unroll
  for (int i = 0; i < 4; ++i)
#pragma unroll
    for (int j = 0; j < 4; ++j) {
      int col = n0 + wn + j * 16 + l15;
#pragma unroll
      for (int r = 0; r < 4; ++r) {
        int row = m0 + wm + i * 16 + l4 * 4 + r;
        float v = acc[i][j][r];
        if (EPI == 0) {
          ((bf16*)Cout)[(size_t)row * N + col] = (bf16)(v + bias[col]);
        } else if (EPI == 1) {
          size_t idx = (size_t)row * N + col;
          ((float*)Cout)[idx] = v + bias[row] + resid[idx];
        } else {
          ((bf16*)Cout)[(size_t)row * N + col] = (bf16)(v + bias[row]);
        }
      }
    }
}

// ---------------- flash attention, frame-block causal, 256 uniform blocks ----------------
// Frame f: 8 q-subtiles (128 rows) x np(f) kv-parts, np = {1,2,3,4,4,5,6,7} -> 256 blocks.
// 4 waves; wave owns 32 q-rows as two 16-col groups sharing every K/V fragment read.
// K: LDS, XOR-swizzled (chunk ^= row&7) via pre-swizzled global src. V^T: LDS linear.
// Both double-buffered; stage(t+1) issued before compute(t); one barrier per tile.
__global__ __launch_bounds__(256, 1) void attn_kernel(const bf16* __restrict__ Qg,
                                                      const bf16* __restrict__ Kg,
                                                      const bf16* __restrict__ VT,
                                                      bf16* __restrict__ Oat,
                                                      bf16* __restrict__ Opart,
                                                      float2* __restrict__ mlbuf) {
  const float SC2 = 1.4426950408889634f / 22.627416997969522f;  // (1/sqrt(512))*log2(e)
  __shared__ bf16 k_lds[2][32 * 512];   // 64KB, swizzled rows
  __shared__ bf16 vt_lds[2][512 * 32];  // 64KB, linear [d][kv]
  __shared__ u32 p_lds[4][2][16 * 20];  // 10.25KB per-wave P rows

  // XCD swizzle: physical d -> logical (d&7)*32 + d>>3 puts 8 q-siblings on one XCD
  int b = (blockIdx.x & 7) * 32 + (blockIdx.x >> 3);
  int f = 0, cxe = 0, np = 1;
  while (b >= 8 * np) { b -= 8 * np; cxe += np - 1; ++f; np = (f < 4) ? f + 1 : f; }
  int p = b >> 3, qi = b & 7;
  int q0 = f * 1024 + qi * 128;
  int ntf = (f + 1) * 32;
  int t0 = (p * ntf) / np, t1 = ((p + 1) * ntf) / np;

  int tid = threadIdx.x, wid = tid >> 6, lane = tid & 63;
  int l15 = lane & 15, l4 = lane >> 4;

  // Q registers: two 16-row groups per wave
  int qrl = q0 + wid * 32 + l15;
  bf16x8 qlo[16], qhi[16];
#pragma unroll
  for (int ks = 0; ks < 16; ++ks) {
    qlo[ks] = *(const bf16x8*)(Qg + (size_t)qrl * 512 + ks * 32 + l4 * 8);
    qhi[ks] = *(const bf16x8*)(Qg + (size_t)(qrl + 16) * 512 + ks * 32 + l4 * 8);
  }

  f32x4 oacc[32][2];
#pragma unroll
  for (int i = 0; i < 32; ++i) {
    oacc[i][0] = (f32x4){0.f, 0.f, 0.f, 0.f};
    oacc[i][1] = (f32x4){0.f, 0.f, 0.f, 0.f};
  }
  float m2a = -1e30f, lsa = 0.f, m2b = -1e30f, lsb = 0.f;

  // stage one 32-kv tile: 8 K rows + 8 V chunks per wave (16 x 1KB global_load_lds)
  auto stage = [&](int buf, int t) {
    int kv0 = t * 32;
#pragma unroll
    for (int i = 0; i < 8; ++i) {
      int rr = wid * 8 + i;
      // K row rr: source chunk pre-swizzled so LDS[rr][c'] = global chunk c'^(rr&7)
      async_copy16(Kg + (((size_t)(kv0 + rr)) << 9) + ((lane ^ (rr & 7)) << 3),
                   &k_lds[buf][rr << 9]);
      // V chunk rr: 16 d-rows x 32 kv, linear
      async_copy16(VT + (size_t)(rr * 16 + (lane >> 2)) * 8192 + kv0 + ((lane & 3) << 3),
                   &vt_lds[buf][rr << 9]);
    }
  };

  stage(0, t0);
  __syncthreads();

  int sw = l15 & 7;
  for (int t = t0; t < t1; ++t) {
    int cur = (t - t0) & 1;
    if (t + 1 < t1) stage(cur ^ 1, t + 1);

    // QK^T -> S^T[kv 32][q 16] x 2 q-groups (each K fragment feeds 2 MFMAs)
    f32x4 s00 = {0.f, 0.f, 0.f, 0.f}, s01 = s00, s10 = s00, s11 = s00;
    const bf16* kb = k_lds[cur];
#pragma unroll
    for (int ks = 0; ks < 16; ++ks) {
      int c0 = ((ks * 4 + l4) ^ sw) << 3;
      bf16x8 a0 = *(const bf16x8*)(kb + (l15 << 9) + c0);
      bf16x8 a1 = *(const bf16x8*)(kb + ((l15 + 16) << 9) + c0);
      s00 = MFMA16(a0, qlo[ks], s00);
      s01 = MFMA16(a0, qhi[ks], s01);
      s10 = MFMA16(a1, qlo[ks], s10);
      s11 = MFMA16(a1, qhi[ks], s11);
    }

    // online softmax, group lo (s00,s10) and hi (s01,s11); column q = l15
    float pm0 = -1e30f, pm1 = -1e30f;
#pragma unroll
    for (int r = 0; r < 4; ++r) {
      pm0 = fmaxf(pm0, fmaxf(s00[r], s10[r]));
      pm1 = fmaxf(pm1, fmaxf(s01[r], s11[r]));
    }
    pm0 = fmaxf(pm0, __shfl_xor(pm0, 16)); pm0 = fmaxf(pm0, __shfl_xor(pm0, 32));
    pm1 = fmaxf(pm1, __shfl_xor(pm1, 16)); pm1 = fmaxf(pm1, __shfl_xor(pm1, 32));
    pm0 *= SC2; pm1 *= SC2;
    bool skip0 = (m2a > -1e29f) && (__all(pm0 <= m2a + 11.5415603f) != 0);
    bool skip1 = (m2b > -1e29f) && (__all(pm1 <= m2b + 11.5415603f) != 0);
    float n0 = skip0 ? m2a : fmaxf(m2a, pm0);
    float n1 = skip1 ? m2b : fmaxf(m2b, pm1);
    float pr0[8], pr1[8], ps0 = 0.f, ps1 = 0.f;
#pragma unroll
    for (int r = 0; r < 4; ++r) {
      pr0[r] = exp2f(s00[r] * SC2 - n0);
      pr0[4 + r] = exp2f(s10[r] * SC2 - n0);
      pr1[r] = exp2f(s01[r] * SC2 - n1);
      pr1[4 + r] = exp2f(s11[r] * SC2 - n1);
      ps0 += pr0[r] + pr0[4 + r];
      ps1 += pr1[r] + pr1[4 + r];
    }
    ps0 += __shfl_xor(ps0, 16); ps0 += __shfl_xor(ps0, 32);
    ps1 += __shfl_xor(ps1, 16); ps1 += __shfl_xor(ps1, 32);
    if (!skip0) {
      float corr = exp2f(m2a - n0);
      lsa *= corr;
#pragma unroll
      for (int i = 0; i < 32; ++i) oacc[i][0] *= corr;
      m2a = n0;
    }
    lsa += ps0;
    if (!skip1) {
      float corr = exp2f(m2b - n1);
      lsb *= corr;
#pragma unroll
      for (int i = 0; i < 32; ++i) oacc[i][1] *= corr;
      m2b = n1;
    }
    lsb += ps1;

    // P -> p_lds (packed kv-pair dwords), wave-private
    u32* pr0w = &p_lds[wid][0][l15 * 20];
    u32* pr1w = &p_lds[wid][1][l15 * 20];
    *(u32x2*)(pr0w + l4 * 2) = (u32x2){pack2(pr0[0], pr0[1]), pack2(pr0[2], pr0[3])};
    *(u32x2*)(pr0w + l4 * 2 + 8) = (u32x2){pack2(pr0[4], pr0[5]), pack2(pr0[6], pr0[7])};
    *(u32x2*)(pr1w + l4 * 2) = (u32x2){pack2(pr1[0], pr1[1]), pack2(pr1[2], pr1[3])};
    *(u32x2*)(pr1w + l4 * 2 + 8) = (u32x2){pack2(pr1[4], pr1[5]), pack2(pr1[6], pr1[7])};
    bf16x8 pf0 = *(bf16x8*)(pr0w + l4 * 4);
    bf16x8 pf1 = *(bf16x8*)(pr1w + l4 * 4);

    // PV: O^T[d][q] += V^T[d][kv] * P[kv][q]; each V fragment feeds 2 MFMAs
    const bf16* vb = vt_lds[cur];
#pragma unroll
    for (int df = 0; df < 32; ++df) {
      bf16x8 vf = *(const bf16x8*)(vb + (df * 16 + l15) * 32 + l4 * 8);
      oacc[df][0] = MFMA16(vf, pf0, oacc[df][0]);
      oacc[df][1] = MFMA16(vf, pf1, oacc[df][1]);
    }

    __syncthreads();  // drains stage(t+1) vmem + all lds reads; buffers swap safely
  }

  // write unnormalized partials (lane: q=l15 in each group, d = df*16 + l4*4 + reg)
#pragma unroll
  for (int qh = 0; qh < 2; ++qh) {
    int qr = q0 + wid * 32 + qh * 16 + l15;
    bf16* op = (p == 0) ? Oat + (size_t)qr * 512
                        : Opart + ((size_t)(cxe + p - 1) * 1024 + (qr & 1023)) * 512;
#pragma unroll
    for (int df = 0; df < 32; ++df) {
      f32x4 o = qh ? oacc[df][1] : oacc[df][0];
      u32x2 w2 = {pack2(o[0], o[1]), pack2(o[2], o[3])};
      *(u32x2*)(op + df * 16 + l4 * 4) = w2;
    }
    if (l4 == 0) mlbuf[p * 8192 + qr] = make_float2(qh ? m2b : m2a, qh ? lsb : lsa);
  }
}

// ---------------- merge np(f) partials per row + normalize ----------------
__global__ void combine_kernel(const bf16* __restrict__ Opart, const float2* __restrict__ ml,
                               bf16* __restrict__ O) {
  int i = blockIdx.x * 256 + threadIdx.x;  // 8192 rows * 64 chunks of 8
  int row = i >> 6, dc = (i & 63) * 8;
  int f = row >> 10;
  int np = f + (f < 4 ? 1 : 0);
  int cxe = f * (f - 1) / 2 - (f > 4 ? f - 4 : 0);
  float2 m0 = ml[row];
  float mm = m0.x;
  for (int p = 1; p < np; ++p) mm = fmaxf(mm, ml[p * 8192 + row].x);
  float acc[8];
  float denom;
  {
    float w = exp2f(m0.x - mm);
    denom = w * m0.y;
    bf16x8 o = *(const bf16x8*)(O + (size_t)row * 512 + dc);
#pragma unroll
    for (int j = 0; j < 8; ++j) acc[j] = w * (float)o[j];
  }
  int rowin = row & 1023;
  for (int p = 1; p < np; ++p) {
    float2 mp = ml[p * 8192 + row];
    float w = exp2f(mp.x - mm);
    denom += w * mp.y;
    bf16x8 o = *(const bf16x8*)(Opart + ((size_t)(cxe + p - 1) * 1024 + rowin) * 512 + dc);
#pragma unroll
    for (int j = 0; j < 8; ++j) acc[j] += w * (float)o[j];
  }
  float inv = 1.f / denom;
  bf16x8 r;
#pragma unroll
  for (int j = 0; j < 8; ++j) r[j] = (bf16)(acc[j] * inv);
  *(bf16x8*)(O + (size_t)row * 512 + dc) = r;
}

extern "C" void kernel_launch(void* const* d_in, const int* in_sizes, int n_in, void* d_out,
                              int out_size, void* d_ws, size_t ws_size, hipStream_t stream) {
  (void)in_sizes; (void)n_in; (void)out_size; (void)ws_size;
  const float* x = (const float*)d_in[0];
  const float* gamma = (const float*)d_in[1];
  const float* wq = (const float*)d_in[2];
  const float* bq = (const float*)d_in[3];
  const float* wk = (const float*)d_in[4];
  const float* bk = (const float*)d_in[5];
  const float* wv = (const float*)d_in[6];
  const float* bv = (const float*)d_in[7];
  const float* wo = (const float*)d_in[8];
  const float* bo = (const float*)d_in[9];

  const size_t SC = (size_t)8192 * 512;
  bf16* wq_b = (bf16*)d_ws;            // 4 x 512KB = 2MB
  bf16* wk_b = wq_b + 262144;
  bf16* wv_b = wk_b + 262144;
  bf16* wo_b = wv_b + 262144;
  bf16* xn_oat = wo_b + 262144;        // 8MB: xn, later attn output (+partial 0)
  bf16* q = xn_oat + SC;               // 8MB
  bf16* k = q + SC;                    // 8MB
  bf16* vt = k + SC;                   // 8MB, V^T [512][8192]
  bf16* opart = vt + SC;               // 24 x 1024 rows x 512 bf16 = 24MB (partials 1..np-1)
  float2* ml = (float2*)(opart + (size_t)24 * 1024 * 512);  // 7*8192 float2 = 448KB

  cvt_w_kernel<<<1024, 256, 0, stream>>>(wq, wk, wv, wo, wq_b);
  rmsnorm_kernel<<<128, 256, 0, stream>>>(x, gamma, xn_oat);
  gemm_nt_kernel<0><<<256, 256, 0, stream>>>(xn_oat, wq_b, bq, nullptr, q, 8192, 512, 4);
  gemm_nt_kernel<0><<<256, 256, 0, stream>>>(xn_oat, wk_b, bk, nullptr, k, 8192, 512, 4);
  gemm_nt_kernel<2><<<256, 256, 0, stream>>>(wv_b, xn_oat, bv, nullptr, vt, 512, 8192, 64);
  attn_kernel<<<256, 256, 0, stream>>>(q, k, vt, xn_oat, opart, ml);
  combine_kernel<<<2048, 256, 0, stream>>>(opart, ml, xn_oat);
  gemm_nt_kernel<1><<<256, 256, 0, stream>>>(wo_b, xn_oat, bo, x, d_out, 512, 8192, 64);
}

// Round 5
// 333.102 us; speedup vs baseline: 2.4687x; 2.4687x over previous
//
#include <hip/hip_runtime.h>
#include <stdint.h>

// HunyuanVideo attn block: rmsnorm -> qkv proj -> frame-causal attention -> out proj + residual
// B=1, C=512, T=8, H=W=32 -> S=8192, frame block = 1024.
// v5: attention = v1's per-wave layout (q=16/wave, ~230 regs, no spill) + v3's staging
//     (global_load_lds dbuf K swizzled + V^T linear) + 512 uniform blocks, XCD-grouped.

typedef __bf16 bf16;
typedef __bf16 bf16x8 __attribute__((ext_vector_type(8)));
typedef float f32x4 __attribute__((ext_vector_type(4)));
typedef uint32_t u32;
typedef uint32_t u32x2 __attribute__((ext_vector_type(2)));

#define MFMA16(a, b, c) __builtin_amdgcn_mfma_f32_16x16x32_bf16((a), (b), (c), 0, 0, 0)

__device__ __forceinline__ u32 pack2(float a, float b) {
  union { bf16 h[2]; u32 u; } x;
  x.h[0] = (bf16)a;
  x.h[1] = (bf16)b;
  return x.u;
}

__device__ __forceinline__ void async_copy16(const bf16* gsrc, bf16* ldst) {
  __builtin_amdgcn_global_load_lds(
      (const __attribute__((address_space(1))) void*)gsrc,
      (__attribute__((address_space(3))) void*)ldst, 16, 0, 0);
}

// ---------------- weights fp32 -> bf16 ----------------
__global__ void cvt_w_kernel(const float* __restrict__ a, const float* __restrict__ b,
                             const float* __restrict__ c, const float* __restrict__ d,
                             bf16* __restrict__ out) {
  int i = blockIdx.x * 256 + threadIdx.x;
  const int N = 512 * 512;
  out[i]         = (bf16)a[i];
  out[N + i]     = (bf16)b[i];
  out[2 * N + i] = (bf16)c[i];
  out[3 * N + i] = (bf16)d[i];
}

// ---------------- rmsnorm over C + transpose to [S][C] bf16 ----------------
__global__ __launch_bounds__(256) void rmsnorm_kernel(const float* __restrict__ x,
                                                      const float* __restrict__ gamma,
                                                      bf16* __restrict__ xn) {
  const int S = 8192;
  __shared__ float sums[4][64];
  int ts = threadIdx.x & 63, tc = threadIdx.x >> 6;
  int s = blockIdx.x * 64 + ts;
  float acc = 0.f;
  for (int c = tc * 128; c < tc * 128 + 128; ++c) {
    float v = x[(size_t)c * S + s];
    acc += v * v;
  }
  sums[tc][ts] = acc;
  __syncthreads();
  float tot = sums[0][ts] + sums[1][ts] + sums[2][ts] + sums[3][ts];
  float kk = 22.62741699796952f / fmaxf(sqrtf(tot), 1e-12f);
  for (int c0 = tc * 128; c0 < tc * 128 + 128; c0 += 8) {
    bf16x8 o;
#pragma unroll
    for (int j = 0; j < 8; ++j) o[j] = (bf16)(x[(size_t)(c0 + j) * S + s] * kk * gamma[c0 + j]);
    *(bf16x8*)(xn + (size_t)s * 512 + c0) = o;
  }
}

// ---------------- NT GEMM: C[m,n] = sum_k A[m,k]*B[n,k], K=512 ----------------
template <int EPI>
__global__ __launch_bounds__(256) void gemm_nt_kernel(const bf16* __restrict__ A,
                                                      const bf16* __restrict__ B,
                                                      const float* __restrict__ bias,
                                                      const float* __restrict__ resid,
                                                      void* __restrict__ Cout, int M, int N,
                                                      int nbn) {
  __shared__ bf16 a_lds[128 * 72];
  __shared__ bf16 b_lds[128 * 72];
  const int K = 512;
  int bm = blockIdx.x / nbn, bn = blockIdx.x % nbn;
  int m0 = bm * 128, n0 = bn * 128;
  int tid = threadIdx.x, lane = tid & 63;
  int wid = tid >> 6;
  int wm = (wid >> 1) * 64, wn = (wid & 1) * 64;
  int l15 = lane & 15, l4 = lane >> 4;
  f32x4 acc[4][4];
#pragma unroll
  for (int i = 0; i < 4; ++i)
#pragma unroll
    for (int j = 0; j < 4; ++j) acc[i][j] = (f32x4){0.f, 0.f, 0.f, 0.f};

  for (int k0 = 0; k0 < K; k0 += 64) {
    __syncthreads();
#pragma unroll
    for (int i = 0; i < 4; ++i) {
      int lin = i * 2048 + tid * 8;
      int r = lin >> 6, c = lin & 63;
      *(bf16x8*)(a_lds + r * 72 + c) = *(const bf16x8*)(A + (size_t)(m0 + r) * K + k0 + c);
      *(bf16x8*)(b_lds + r * 72 + c) = *(const bf16x8*)(B + (size_t)(n0 + r) * K + k0 + c);
    }
    __syncthreads();
#pragma unroll
    for (int kk = 0; kk < 2; ++kk) {
      bf16x8 af[4], bfr[4];
#pragma unroll
      for (int i = 0; i < 4; ++i)
        af[i] = *(bf16x8*)(a_lds + (wm + i * 16 + l15) * 72 + kk * 32 + l4 * 8);
#pragma unroll
      for (int j = 0; j < 4; ++j)
        bfr[j] = *(bf16x8*)(b_lds + (wn + j * 16 + l15) * 72 + kk * 32 + l4 * 8);
#pragma unroll
      for (int i = 0; i < 4; ++i)
#pragma unroll
        for (int j = 0; j < 4; ++j) acc[i][j] = MFMA16(af[i], bfr[j], acc[i][j]);
    }
  }
#pragma unroll
  for (int i = 0; i < 4; ++i)
#pragma unroll
    for (int j = 0; j < 4; ++j) {
      int col = n0 + wn + j * 16 + l15;
#pragma unroll
      for (int r = 0; r < 4; ++r) {
        int row = m0 + wm + i * 16 + l4 * 4 + r;
        float v = acc[i][j][r];
        if (EPI == 0) {
          ((bf16*)Cout)[(size_t)row * N + col] = (bf16)(v + bias[col]);
        } else if (EPI == 1) {
          size_t idx = (size_t)row * N + col;
          ((float*)Cout)[idx] = v + bias[row] + resid[idx];
        } else {
          ((bf16*)Cout)[(size_t)row * N + col] = (bf16)(v + bias[row]);
        }
      }
    }
}

// ---------------- flash attention, frame-block causal, 512 uniform blocks ----------------
// Frame f: 16 q-subtiles (64 rows) x np(f) kv-parts, np = {1,2,3,4,4,5,6,7} -> 512 blocks.
// 4 waves; each wave owns 16 q rows (v1 layout: qreg 64 + oacc 128 regs, no spill).
// K: LDS, XOR-swizzled via pre-swizzled global src. V^T: LDS linear [d][32kv].
// Both double-buffered via global_load_lds; stage(t+1) before compute(t); 1 barrier/tile.
__global__ __launch_bounds__(256, 1) void attn_kernel(const bf16* __restrict__ Qg,
                                                      const bf16* __restrict__ Kg,
                                                      const bf16* __restrict__ VT,
                                                      bf16* __restrict__ Oat,
                                                      bf16* __restrict__ Opart,
                                                      float2* __restrict__ mlbuf) {
  const float SC2 = 1.4426950408889634f / 22.627416997969522f;  // (1/sqrt(512))*log2(e)
  __shared__ bf16 k_lds[2][32 * 512];   // 64KB, rows chunk-swizzled (chunk ^= row&7)
  __shared__ bf16 vt_lds[2][512 * 32];  // 64KB, linear [d][kv]
  __shared__ u32 p_lds[4][16 * 20];     // 5KB per-wave P rows (packed kv-pair dwords)

  // XCD swizzle: 16 q-siblings of each (f,p) group land on one XCD (512 = 8 x 64)
  int b = (blockIdx.x & 7) * 64 + (blockIdx.x >> 3);
  int f = 0, cxe = 0, np = 1;
  while (b >= 16 * np) { b -= 16 * np; cxe += np - 1; ++f; np = (f < 4) ? f + 1 : f; }
  int p = b >> 4, qi = b & 15;
  int q0 = f * 1024 + qi * 64;
  int ntf = (f + 1) * 32;
  int t0 = (p * ntf) / np, t1 = ((p + 1) * ntf) / np;

  int tid = threadIdx.x, wid = tid >> 6, lane = tid & 63;
  int l15 = lane & 15, l4 = lane >> 4;

  int qrow = q0 + wid * 16 + l15;
  bf16x8 qreg[16];
#pragma unroll
  for (int ks = 0; ks < 16; ++ks)
    qreg[ks] = *(const bf16x8*)(Qg + (size_t)qrow * 512 + ks * 32 + l4 * 8);

  f32x4 oacc[32];
#pragma unroll
  for (int i = 0; i < 32; ++i) oacc[i] = (f32x4){0.f, 0.f, 0.f, 0.f};
  float m2 = -1e30f, lsum = 0.f;

  // stage one 32-kv tile: 8 K rows + 8 V chunks per wave (16 x 1KB global_load_lds)
  auto stage = [&](int buf, int t) {
    int kv0 = t * 32;
#pragma unroll
    for (int i = 0; i < 8; ++i) {
      int rr = wid * 8 + i;
      // K row rr: LDS chunk c' holds global chunk c'^(rr&7)
      async_copy16(Kg + (((size_t)(kv0 + rr)) << 9) + ((lane ^ (rr & 7)) << 3),
                   &k_lds[buf][rr << 9]);
      // V chunk rr: d-rows [rr*16, rr*16+16), 32 kv each, linear
      async_copy16(VT + (size_t)(rr * 16 + (lane >> 2)) * 8192 + kv0 + ((lane & 3) << 3),
                   &vt_lds[buf][rr << 9]);
    }
  };

  stage(0, t0);
  __syncthreads();

  int sw = l15 & 7;
  for (int t = t0; t < t1; ++t) {
    int cur = (t - t0) & 1;
    if (t + 1 < t1) stage(cur ^ 1, t + 1);

    // QK^T -> S^T[kv 32][q 16], K fragments via swizzled read
    f32x4 sacc0 = {0.f, 0.f, 0.f, 0.f}, sacc1 = sacc0;
    const bf16* kb = k_lds[cur];
#pragma unroll
    for (int ks = 0; ks < 16; ++ks) {
      int c0 = ((ks * 4 + l4) ^ sw) << 3;
      bf16x8 a0 = *(const bf16x8*)(kb + (l15 << 9) + c0);
      bf16x8 a1 = *(const bf16x8*)(kb + ((l15 + 16) << 9) + c0);
      sacc0 = MFMA16(a0, qreg[ks], sacc0);
      sacc1 = MFMA16(a1, qreg[ks], sacc1);
    }

    // online softmax for column q = l15
    float pmax = -1e30f;
#pragma unroll
    for (int r = 0; r < 4; ++r) {
      pmax = fmaxf(pmax, sacc0[r]);
      pmax = fmaxf(pmax, sacc1[r]);
    }
    pmax = fmaxf(pmax, __shfl_xor(pmax, 16));
    pmax = fmaxf(pmax, __shfl_xor(pmax, 32));
    pmax *= SC2;
    bool skip = (m2 > -1e29f) && (__all(pmax <= m2 + 11.5415603f) != 0);  // defer-max THR=8
    float m2n = skip ? m2 : fmaxf(m2, pmax);
    float pr[8];
    float psum = 0.f;
#pragma unroll
    for (int r = 0; r < 4; ++r) {
      pr[r] = exp2f(sacc0[r] * SC2 - m2n);
      pr[4 + r] = exp2f(sacc1[r] * SC2 - m2n);
      psum += pr[r] + pr[4 + r];
    }
    psum += __shfl_xor(psum, 16);
    psum += __shfl_xor(psum, 32);
    if (!skip) {
      float corr = exp2f(m2 - m2n);
      lsum = lsum * corr;
#pragma unroll
      for (int i = 0; i < 32; ++i) oacc[i] *= corr;
      m2 = m2n;
    }
    lsum += psum;

    // P -> p_lds[q][kv] (packed dwords), wave-private
    u32* prow = &p_lds[wid][l15 * 20];
    *(u32x2*)(prow + l4 * 2) = (u32x2){pack2(pr[0], pr[1]), pack2(pr[2], pr[3])};
    *(u32x2*)(prow + l4 * 2 + 8) = (u32x2){pack2(pr[4], pr[5]), pack2(pr[6], pr[7])};
    bf16x8 pfrag = *(bf16x8*)(prow + l4 * 4);

    // PV: O^T[d][q] += V^T[d][kv] * P[kv][q]
    const bf16* vb = vt_lds[cur];
#pragma unroll
    for (int df = 0; df < 32; ++df) {
      bf16x8 vf = *(const bf16x8*)(vb + (df * 16 + l15) * 32 + l4 * 8);
      oacc[df] = MFMA16(vf, pfrag, oacc[df]);
    }

    __syncthreads();  // drains stage(t+1) vmem + all lds reads; buffers swap safely
  }

  // write unnormalized partial (lane: q=l15, d = df*16 + l4*4 + reg)
  int qr = q0 + wid * 16 + l15;
  bf16* op = (p == 0) ? Oat + (size_t)qr * 512
                      : Opart + ((size_t)(cxe + p - 1) * 1024 + (qr & 1023)) * 512;
#pragma unroll
  for (int df = 0; df < 32; ++df) {
    u32x2 w2 = {pack2(oacc[df][0], oacc[df][1]), pack2(oacc[df][2], oacc[df][3])};
    *(u32x2*)(op + df * 16 + l4 * 4) = w2;
  }
  if (l4 == 0) mlbuf[p * 8192 + qr] = make_float2(m2, lsum);
}

// ---------------- merge np(f) partials per row + normalize ----------------
__global__ void combine_kernel(const bf16* __restrict__ Opart, const float2* __restrict__ ml,
                               bf16* __restrict__ O) {
  int i = blockIdx.x * 256 + threadIdx.x;  // 8192 rows * 64 chunks of 8
  int row = i >> 6, dc = (i & 63) * 8;
  int f = row >> 10;
  int np = f + (f < 4 ? 1 : 0);
  int cxe = f * (f - 1) / 2 - (f > 4 ? f - 4 : 0);
  float2 m0 = ml[row];
  float mm = m0.x;
  for (int p = 1; p < np; ++p) mm = fmaxf(mm, ml[p * 8192 + row].x);
  float acc[8];
  float denom;
  {
    float w = exp2f(m0.x - mm);
    denom = w * m0.y;
    bf16x8 o = *(const bf16x8*)(O + (size_t)row * 512 + dc);
#pragma unroll
    for (int j = 0; j < 8; ++j) acc[j] = w * (float)o[j];
  }
  int rowin = row & 1023;
  for (int p = 1; p < np; ++p) {
    float2 mp = ml[p * 8192 + row];
    float w = exp2f(mp.x - mm);
    denom += w * mp.y;
    bf16x8 o = *(const bf16x8*)(Opart + ((size_t)(cxe + p - 1) * 1024 + rowin) * 512 + dc);
#pragma unroll
    for (int j = 0; j < 8; ++j) acc[j] += w * (float)o[j];
  }
  float inv = 1.f / denom;
  bf16x8 r;
#pragma unroll
  for (int j = 0; j < 8; ++j) r[j] = (bf16)(acc[j] * inv);
  *(bf16x8*)(O + (size_t)row * 512 + dc) = r;
}

extern "C" void kernel_launch(void* const* d_in, const int* in_sizes, int n_in, void* d_out,
                              int out_size, void* d_ws, size_t ws_size, hipStream_t stream) {
  (void)in_sizes; (void)n_in; (void)out_size; (void)ws_size;
  const float* x = (const float*)d_in[0];
  const float* gamma = (const float*)d_in[1];
  const float* wq = (const float*)d_in[2];
  const float* bq = (const float*)d_in[3];
  const float* wk = (const float*)d_in[4];
  const float* bk = (const float*)d_in[5];
  const float* wv = (const float*)d_in[6];
  const float* bv = (const float*)d_in[7];
  const float* wo = (const float*)d_in[8];
  const float* bo = (const float*)d_in[9];

  const size_t SC = (size_t)8192 * 512;
  bf16* wq_b = (bf16*)d_ws;            // 4 x 512KB = 2MB
  bf16* wk_b = wq_b + 262144;
  bf16* wv_b = wk_b + 262144;
  bf16* wo_b = wv_b + 262144;
  bf16* xn_oat = wo_b + 262144;        // 8MB: xn, later attn output (+partial 0)
  bf16* q = xn_oat + SC;               // 8MB
  bf16* k = q + SC;                    // 8MB
  bf16* vt = k + SC;                   // 8MB, V^T [512][8192]
  bf16* opart = vt + SC;               // 24 x 1024 rows x 512 bf16 = 24MB (partials 1..np-1)
  float2* ml = (float2*)(opart + (size_t)24 * 1024 * 512);  // 7*8192 float2 = 448KB

  cvt_w_kernel<<<1024, 256, 0, stream>>>(wq, wk, wv, wo, wq_b);
  rmsnorm_kernel<<<128, 256, 0, stream>>>(x, gamma, xn_oat);
  gemm_nt_kernel<0><<<256, 256, 0, stream>>>(xn_oat, wq_b, bq, nullptr, q, 8192, 512, 4);
  gemm_nt_kernel<0><<<256, 256, 0, stream>>>(xn_oat, wk_b, bk, nullptr, k, 8192, 512, 4);
  gemm_nt_kernel<2><<<256, 256, 0, stream>>>(wv_b, xn_oat, bv, nullptr, vt, 512, 8192, 64);
  attn_kernel<<<512, 256, 0, stream>>>(q, k, vt, xn_oat, opart, ml);
  combine_kernel<<<2048, 256, 0, stream>>>(opart, ml, xn_oat);
  gemm_nt_kernel<1><<<256, 256, 0, stream>>>(wo_b, xn_oat, bo, x, d_out, 512, 8192, 64);
}

// Round 6
// 260.542 us; speedup vs baseline: 3.1563x; 1.2785x over previous
//
#include <hip/hip_runtime.h>
#include <stdint.h>

// HunyuanVideo attn block: rmsnorm -> qkv proj -> frame-causal attention -> out proj + residual
// B=1, C=512, T=8, H=W=32 -> S=8192, frame block = 1024.
// v6 = v5 + (a) V^T LDS XOR-swizzle swz(d)=(d>>1)&3 (kills 8-way PV bank conflict),
//          (b) single-buffered K/V -> 69.4KB LDS -> 2 blocks/CU (cross-block latency hiding).

typedef __bf16 bf16;
typedef __bf16 bf16x8 __attribute__((ext_vector_type(8)));
typedef float f32x4 __attribute__((ext_vector_type(4)));
typedef uint32_t u32;
typedef uint32_t u32x2 __attribute__((ext_vector_type(2)));

#define MFMA16(a, b, c) __builtin_amdgcn_mfma_f32_16x16x32_bf16((a), (b), (c), 0, 0, 0)

__device__ __forceinline__ u32 pack2(float a, float b) {
  union { bf16 h[2]; u32 u; } x;
  x.h[0] = (bf16)a;
  x.h[1] = (bf16)b;
  return x.u;
}

__device__ __forceinline__ void async_copy16(const bf16* gsrc, bf16* ldst) {
  __builtin_amdgcn_global_load_lds(
      (const __attribute__((address_space(1))) void*)gsrc,
      (__attribute__((address_space(3))) void*)ldst, 16, 0, 0);
}

// ---------------- weights fp32 -> bf16 ----------------
__global__ void cvt_w_kernel(const float* __restrict__ a, const float* __restrict__ b,
                             const float* __restrict__ c, const float* __restrict__ d,
                             bf16* __restrict__ out) {
  int i = blockIdx.x * 256 + threadIdx.x;
  const int N = 512 * 512;
  out[i]         = (bf16)a[i];
  out[N + i]     = (bf16)b[i];
  out[2 * N + i] = (bf16)c[i];
  out[3 * N + i] = (bf16)d[i];
}

// ---------------- rmsnorm over C + transpose to [S][C] bf16 ----------------
__global__ __launch_bounds__(256) void rmsnorm_kernel(const float* __restrict__ x,
                                                      const float* __restrict__ gamma,
                                                      bf16* __restrict__ xn) {
  const int S = 8192;
  __shared__ float sums[4][64];
  int ts = threadIdx.x & 63, tc = threadIdx.x >> 6;
  int s = blockIdx.x * 64 + ts;
  float acc = 0.f;
  for (int c = tc * 128; c < tc * 128 + 128; ++c) {
    float v = x[(size_t)c * S + s];
    acc += v * v;
  }
  sums[tc][ts] = acc;
  __syncthreads();
  float tot = sums[0][ts] + sums[1][ts] + sums[2][ts] + sums[3][ts];
  float kk = 22.62741699796952f / fmaxf(sqrtf(tot), 1e-12f);
  for (int c0 = tc * 128; c0 < tc * 128 + 128; c0 += 8) {
    bf16x8 o;
#pragma unroll
    for (int j = 0; j < 8; ++j) o[j] = (bf16)(x[(size_t)(c0 + j) * S + s] * kk * gamma[c0 + j]);
    *(bf16x8*)(xn + (size_t)s * 512 + c0) = o;
  }
}

// ---------------- NT GEMM: C[m,n] = sum_k A[m,k]*B[n,k], K=512 ----------------
template <int EPI>
__global__ __launch_bounds__(256) void gemm_nt_kernel(const bf16* __restrict__ A,
                                                      const bf16* __restrict__ B,
                                                      const float* __restrict__ bias,
                                                      const float* __restrict__ resid,
                                                      void* __restrict__ Cout, int M, int N,
                                                      int nbn) {
  __shared__ bf16 a_lds[128 * 72];
  __shared__ bf16 b_lds[128 * 72];
  const int K = 512;
  int bm = blockIdx.x / nbn, bn = blockIdx.x % nbn;
  int m0 = bm * 128, n0 = bn * 128;
  int tid = threadIdx.x, lane = tid & 63;
  int wid = tid >> 6;
  int wm = (wid >> 1) * 64, wn = (wid & 1) * 64;
  int l15 = lane & 15, l4 = lane >> 4;
  f32x4 acc[4][4];
#pragma unroll
  for (int i = 0; i < 4; ++i)
#pragma unroll
    for (int j = 0; j < 4; ++j) acc[i][j] = (f32x4){0.f, 0.f, 0.f, 0.f};

  for (int k0 = 0; k0 < K; k0 += 64) {
    __syncthreads();
#pragma unroll
    for (int i = 0; i < 4; ++i) {
      int lin = i * 2048 + tid * 8;
      int r = lin >> 6, c = lin & 63;
      *(bf16x8*)(a_lds + r * 72 + c) = *(const bf16x8*)(A + (size_t)(m0 + r) * K + k0 + c);
      *(bf16x8*)(b_lds + r * 72 + c) = *(const bf16x8*)(B + (size_t)(n0 + r) * K + k0 + c);
    }
    __syncthreads();
#pragma unroll
    for (int kk = 0; kk < 2; ++kk) {
      bf16x8 af[4], bfr[4];
#pragma unroll
      for (int i = 0; i < 4; ++i)
        af[i] = *(bf16x8*)(a_lds + (wm + i * 16 + l15) * 72 + kk * 32 + l4 * 8);
#pragma unroll
      for (int j = 0; j < 4; ++j)
        bfr[j] = *(bf16x8*)(b_lds + (wn + j * 16 + l15) * 72 + kk * 32 + l4 * 8);
#pragma unroll
      for (int i = 0; i < 4; ++i)
#pragma unroll
        for (int j = 0; j < 4; ++j) acc[i][j] = MFMA16(af[i], bfr[j], acc[i][j]);
    }
  }
#pragma unroll
  for (int i = 0; i < 4; ++i)
#pragma unroll
    for (int j = 0; j < 4; ++j) {
      int col = n0 + wn + j * 16 + l15;
#pragma unroll
      for (int r = 0; r < 4; ++r) {
        int row = m0 + wm + i * 16 + l4 * 4 + r;
        float v = acc[i][j][r];
        if (EPI == 0) {
          ((bf16*)Cout)[(size_t)row * N + col] = (bf16)(v + bias[col]);
        } else if (EPI == 1) {
          size_t idx = (size_t)row * N + col;
          ((float*)Cout)[idx] = v + bias[row] + resid[idx];
        } else {
          ((bf16*)Cout)[(size_t)row * N + col] = (bf16)(v + bias[row]);
        }
      }
    }
}

// ---------------- flash attention, frame-block causal, 512 uniform blocks ----------------
// Frame f: 16 q-subtiles (64 rows) x np(f) kv-parts, np = {1,2,3,4,4,5,6,7} -> 512 blocks.
// 4 waves; each wave owns 16 q rows (qreg 64 + oacc 128 regs, no spill).
// K: LDS single-buf, chunk-swizzled (chunk ^= row&7). V^T: LDS single-buf, chunk ^= (d>>1)&3.
// 69.4KB LDS -> 2 blocks/CU; stage latency hidden by the co-resident block.
__global__ __launch_bounds__(256, 2) void attn_kernel(const bf16* __restrict__ Qg,
                                                      const bf16* __restrict__ Kg,
                                                      const bf16* __restrict__ VT,
                                                      bf16* __restrict__ Oat,
                                                      bf16* __restrict__ Opart,
                                                      float2* __restrict__ mlbuf) {
  const float SC2 = 1.4426950408889634f / 22.627416997969522f;  // (1/sqrt(512))*log2(e)
  __shared__ bf16 k_lds[32 * 512];   // 32KB, rows chunk-swizzled (chunk ^= row&7)
  __shared__ bf16 vt_lds[512 * 32];  // 32KB, [d][kv] chunk-swizzled (chunk ^= (d>>1)&3)
  __shared__ u32 p_lds[4][16 * 20];  // 5KB per-wave P rows (packed kv-pair dwords)

  // XCD swizzle: 16 q-siblings of each (f,p) group land on one XCD (512 = 8 x 64)
  int b = (blockIdx.x & 7) * 64 + (blockIdx.x >> 3);
  int f = 0, cxe = 0, np = 1;
  while (b >= 16 * np) { b -= 16 * np; cxe += np - 1; ++f; np = (f < 4) ? f + 1 : f; }
  int p = b >> 4, qi = b & 15;
  int q0 = f * 1024 + qi * 64;
  int ntf = (f + 1) * 32;
  int t0 = (p * ntf) / np, t1 = ((p + 1) * ntf) / np;

  int tid = threadIdx.x, wid = tid >> 6, lane = tid & 63;
  int l15 = lane & 15, l4 = lane >> 4;

  int qrow = q0 + wid * 16 + l15;
  bf16x8 qreg[16];
#pragma unroll
  for (int ks = 0; ks < 16; ++ks)
    qreg[ks] = *(const bf16x8*)(Qg + (size_t)qrow * 512 + ks * 32 + l4 * 8);

  f32x4 oacc[32];
#pragma unroll
  for (int i = 0; i < 32; ++i) oacc[i] = (f32x4){0.f, 0.f, 0.f, 0.f};
  float m2 = -1e30f, lsum = 0.f;

  // stage one 32-kv tile: 8 K rows + 8 V chunk-groups per wave (16 x 1KB global_load_lds)
  auto stage = [&](int t) {
    int kv0 = t * 32;
#pragma unroll
    for (int i = 0; i < 8; ++i) {
      int rr = wid * 8 + i;
      // K row rr: LDS chunk c' holds global chunk c'^(rr&7)
      async_copy16(Kg + (((size_t)(kv0 + rr)) << 9) + ((lane ^ (rr & 7)) << 3),
                   &k_lds[rr << 9]);
      // V rows [rr*16, rr*16+16): LDS chunk c' of row d holds global chunk c'^((d>>1)&3)
      async_copy16(VT + (size_t)(rr * 16 + (lane >> 2)) * 8192 + kv0 +
                       (((lane & 3) ^ ((lane >> 3) & 3)) << 3),
                   &vt_lds[rr << 9]);
    }
  };

  stage(t0);

  int sw = l15 & 7;            // K read swizzle key (row l15 and l15+16 share it)
  int svw = (l15 >> 1) & 3;    // V read swizzle key for d = df*16 + l15
  for (int t = t0; t < t1; ++t) {
    __syncthreads();  // drains stage(t) vmem: tile t resident

    // QK^T -> S^T[kv 32][q 16], K fragments via swizzled read
    f32x4 sacc0 = {0.f, 0.f, 0.f, 0.f}, sacc1 = sacc0;
#pragma unroll
    for (int ks = 0; ks < 16; ++ks) {
      int c0 = ((ks * 4 + l4) ^ sw) << 3;
      bf16x8 a0 = *(const bf16x8*)(k_lds + (l15 << 9) + c0);
      bf16x8 a1 = *(const bf16x8*)(k_lds + ((l15 + 16) << 9) + c0);
      sacc0 = MFMA16(a0, qreg[ks], sacc0);
      sacc1 = MFMA16(a1, qreg[ks], sacc1);
    }

    // online softmax for column q = l15
    float pmax = -1e30f;
#pragma unroll
    for (int r = 0; r < 4; ++r) {
      pmax = fmaxf(pmax, sacc0[r]);
      pmax = fmaxf(pmax, sacc1[r]);
    }
    pmax = fmaxf(pmax, __shfl_xor(pmax, 16));
    pmax = fmaxf(pmax, __shfl_xor(pmax, 32));
    pmax *= SC2;
    bool skip = (m2 > -1e29f) && (__all(pmax <= m2 + 11.5415603f) != 0);  // defer-max THR=8
    float m2n = skip ? m2 : fmaxf(m2, pmax);
    float pr[8];
    float psum = 0.f;
#pragma unroll
    for (int r = 0; r < 4; ++r) {
      pr[r] = exp2f(sacc0[r] * SC2 - m2n);
      pr[4 + r] = exp2f(sacc1[r] * SC2 - m2n);
      psum += pr[r] + pr[4 + r];
    }
    psum += __shfl_xor(psum, 16);
    psum += __shfl_xor(psum, 32);
    if (!skip) {
      float corr = exp2f(m2 - m2n);
      lsum = lsum * corr;
#pragma unroll
      for (int i = 0; i < 32; ++i) oacc[i] *= corr;
      m2 = m2n;
    }
    lsum += psum;

    // P -> p_lds[q][kv] (packed dwords), wave-private
    u32* prow = &p_lds[wid][l15 * 20];
    *(u32x2*)(prow + l4 * 2) = (u32x2){pack2(pr[0], pr[1]), pack2(pr[2], pr[3])};
    *(u32x2*)(prow + l4 * 2 + 8) = (u32x2){pack2(pr[4], pr[5]), pack2(pr[6], pr[7])};
    bf16x8 pfrag = *(bf16x8*)(prow + l4 * 4);

    // PV: O^T[d][q] += V^T[d][kv] * P[kv][q], swizzled V read (conflict-free)
#pragma unroll
    for (int df = 0; df < 32; ++df) {
      bf16x8 vf = *(const bf16x8*)(vt_lds + (df * 16 + l15) * 32 + ((l4 ^ svw) << 3));
      oacc[df] = MFMA16(vf, pfrag, oacc[df]);
    }

    __syncthreads();  // all LDS reads of tile t done
    if (t + 1 < t1) stage(t + 1);  // overwrite buffer; drains at next top-of-loop barrier
  }

  // write unnormalized partial (lane: q=l15, d = df*16 + l4*4 + reg)
  int qr = q0 + wid * 16 + l15;
  bf16* op = (p == 0) ? Oat + (size_t)qr * 512
                      : Opart + ((size_t)(cxe + p - 1) * 1024 + (qr & 1023)) * 512;
#pragma unroll
  for (int df = 0; df < 32; ++df) {
    u32x2 w2 = {pack2(oacc[df][0], oacc[df][1]), pack2(oacc[df][2], oacc[df][3])};
    *(u32x2*)(op + df * 16 + l4 * 4) = w2;
  }
  if (l4 == 0) mlbuf[p * 8192 + qr] = make_float2(m2, lsum);
}

// ---------------- merge np(f) partials per row + normalize ----------------
__global__ void combine_kernel(const bf16* __restrict__ Opart, const float2* __restrict__ ml,
                               bf16* __restrict__ O) {
  int i = blockIdx.x * 256 + threadIdx.x;  // 8192 rows * 64 chunks of 8
  int row = i >> 6, dc = (i & 63) * 8;
  int f = row >> 10;
  int np = f + (f < 4 ? 1 : 0);
  int cxe = f * (f - 1) / 2 - (f > 4 ? f - 4 : 0);
  float2 m0 = ml[row];
  float mm = m0.x;
  for (int p = 1; p < np; ++p) mm = fmaxf(mm, ml[p * 8192 + row].x);
  float acc[8];
  float denom;
  {
    float w = exp2f(m0.x - mm);
    denom = w * m0.y;
    bf16x8 o = *(const bf16x8*)(O + (size_t)row * 512 + dc);
#pragma unroll
    for (int j = 0; j < 8; ++j) acc[j] = w * (float)o[j];
  }
  int rowin = row & 1023;
  for (int p = 1; p < np; ++p) {
    float2 mp = ml[p * 8192 + row];
    float w = exp2f(mp.x - mm);
    denom += w * mp.y;
    bf16x8 o = *(const bf16x8*)(Opart + ((size_t)(cxe + p - 1) * 1024 + rowin) * 512 + dc);
#pragma unroll
    for (int j = 0; j < 8; ++j) acc[j] += w * (float)o[j];
  }
  float inv = 1.f / denom;
  bf16x8 r;
#pragma unroll
  for (int j = 0; j < 8; ++j) r[j] = (bf16)(acc[j] * inv);
  *(bf16x8*)(O + (size_t)row * 512 + dc) = r;
}

extern "C" void kernel_launch(void* const* d_in, const int* in_sizes, int n_in, void* d_out,
                              int out_size, void* d_ws, size_t ws_size, hipStream_t stream) {
  (void)in_sizes; (void)n_in; (void)out_size; (void)ws_size;
  const float* x = (const float*)d_in[0];
  const float* gamma = (const float*)d_in[1];
  const float* wq = (const float*)d_in[2];
  const float* bq = (const float*)d_in[3];
  const float* wk = (const float*)d_in[4];
  const float* bk = (const float*)d_in[5];
  const float* wv = (const float*)d_in[6];
  const float* bv = (const float*)d_in[7];
  const float* wo = (const float*)d_in[8];
  const float* bo = (const float*)d_in[9];

  const size_t SC = (size_t)8192 * 512;
  bf16* wq_b = (bf16*)d_ws;            // 4 x 512KB = 2MB
  bf16* wk_b = wq_b + 262144;
  bf16* wv_b = wk_b + 262144;
  bf16* wo_b = wv_b + 262144;
  bf16* xn_oat = wo_b + 262144;        // 8MB: xn, later attn output (+partial 0)
  bf16* q = xn_oat + SC;               // 8MB
  bf16* k = q + SC;                    // 8MB
  bf16* vt = k + SC;                   // 8MB, V^T [512][8192]
  bf16* opart = vt + SC;               // 24 x 1024 rows x 512 bf16 = 24MB (partials 1..np-1)
  float2* ml = (float2*)(opart + (size_t)24 * 1024 * 512);  // 7*8192 float2 = 448KB

  cvt_w_kernel<<<1024, 256, 0, stream>>>(wq, wk, wv, wo, wq_b);
  rmsnorm_kernel<<<128, 256, 0, stream>>>(x, gamma, xn_oat);
  gemm_nt_kernel<0><<<256, 256, 0, stream>>>(xn_oat, wq_b, bq, nullptr, q, 8192, 512, 4);
  gemm_nt_kernel<0><<<256, 256, 0, stream>>>(xn_oat, wk_b, bk, nullptr, k, 8192, 512, 4);
  gemm_nt_kernel<2><<<256, 256, 0, stream>>>(wv_b, xn_oat, bv, nullptr, vt, 512, 8192, 64);
  attn_kernel<<<512, 256, 0, stream>>>(q, k, vt, xn_oat, opart, ml);
  combine_kernel<<<2048, 256, 0, stream>>>(opart, ml, xn_oat);
  gemm_nt_kernel<1><<<256, 256, 0, stream>>>(wo_b, xn_oat, bo, x, d_out, 512, 8192, 64);
}